// Round 3
// baseline (2611.720 us; speedup 1.0000x reference)
//
#include <hip/hip_runtime.h>
#include <hip/hip_bf16.h>
#include <cstdint>
#include <cstddef>

typedef unsigned short u16;
typedef unsigned int   u32;

__device__ __forceinline__ float bf2f(u16 v){ return __uint_as_float(((u32)v)<<16); }
__device__ __forceinline__ u16 f2bf(float f){
  u32 x = __float_as_uint(f);
  return (u16)((x + 0x7FFFu + ((x>>16)&1u)) >> 16);   // round-to-nearest-even
}
__device__ __forceinline__ void atomAddF(float* p, float v){ unsafeAtomicAdd(p, v); }

// ---------------- zero helpers ----------------
__global__ void kzero(float* p, int n){
  int i = blockIdx.x*blockDim.x + threadIdx.x;
  if(i < n) p[i] = 0.f;
}
__global__ void kzero4(float4* p, int n){
  int i = blockIdx.x*blockDim.x + threadIdx.x;
  if(i < n) p[i] = make_float4(0.f,0.f,0.f,0.f);
}

// ---------------- degrees + edge importance ----------------
__global__ void kdeg(const int* __restrict__ ei0, const int* __restrict__ ei1,
                     const float* __restrict__ nimp, int* __restrict__ deg,
                     float* __restrict__ imp, int E){
  int e = blockIdx.x*blockDim.x + threadIdx.x;
  if(e >= E) return;
  int u = ei0[e], v = ei1[e];
  atomicAdd(&deg[u], 1);
  atomicAdd(&deg[v], 1);
  imp[e] = fminf(nimp[u], nimp[v]);
}

__global__ void kdinv(const int* __restrict__ deg, float* __restrict__ dinv, int N){
  int i = blockIdx.x*blockDim.x + threadIdx.x;
  if(i >= N) return;
  int d = deg[i];
  dinv[i] = (d > 1) ? (1.f/(float)d) : 0.f;   // deg==1 hyperedges are dropped
}

// ---------------- GEMM: buf[e][d] = sum_k h[e][k] * W[k][d] ----------------
// block = 256 threads, 32 edges/block, 8 outputs/thread.
// FIRST: h = edge_attr(f32, DIN=32) * imp;  else: h = buf rows (bf16, DIN=64), in-place.
template<int DIN, bool FIRST>
__global__ __launch_bounds__(256) void kgemm(const float* __restrict__ srcf,
                                             u16* buf,            // no __restrict__: read+write
                                             const float* __restrict__ W,
                                             const float* __restrict__ imp,
                                             int E){
  __shared__ __align__(16) float wl[DIN*64];
  __shared__ __align__(16) float hl[32*DIN];
  const int t  = threadIdx.x;
  const int e0 = blockIdx.x * 32;
  const int rows = min(32, E - e0);

  for(int i = t; i < DIN*64; i += 256) wl[i] = W[i];

  if(FIRST){
    const float4* srcp = (const float4*)(srcf + (size_t)e0*DIN);
    for(int i = t; i < rows*DIN/4; i += 256){
      float4 v = srcp[i];
      float s = imp[e0 + (4*i)/DIN];
      hl[4*i+0] = v.x*s; hl[4*i+1] = v.y*s; hl[4*i+2] = v.z*s; hl[4*i+3] = v.w*s;
    }
  } else {
    const u32* srcp = (const u32*)(buf + (size_t)e0*DIN);
    for(int i = t; i < rows*DIN/2; i += 256){
      u32 pk = srcp[i];
      hl[2*i]   = bf2f((u16)pk);
      hl[2*i+1] = bf2f((u16)(pk>>16));
    }
  }
  __syncthreads();

  const int d = t & 63, w = t >> 6;
  float acc[8];
  #pragma unroll
  for(int j = 0; j < 8; j++) acc[j] = 0.f;

  for(int k = 0; k < DIN; k += 4){
    float w0 = wl[(k+0)*64 + d];
    float w1 = wl[(k+1)*64 + d];
    float w2 = wl[(k+2)*64 + d];
    float w3 = wl[(k+3)*64 + d];
    #pragma unroll
    for(int j = 0; j < 8; j++){
      float4 hv = *(const float4*)&hl[(w*8 + j)*DIN + k];
      acc[j] = fmaf(hv.x, w0, acc[j]);
      acc[j] = fmaf(hv.y, w1, acc[j]);
      acc[j] = fmaf(hv.z, w2, acc[j]);
      acc[j] = fmaf(hv.w, w3, acc[j]);
    }
  }
  const size_t ob = (size_t)(e0 + w*8)*64 + d;
  #pragma unroll
  for(int j = 0; j < 8; j++){
    if(w*8 + j < rows) buf[ob + (size_t)j*64] = f2bf(acc[j]);
  }
}

// ---------------- scatter: he[node] += xw[edge] for both endpoints ----------------
__global__ __launch_bounds__(256) void kscatter(const u16* __restrict__ buf,
                                                const int* __restrict__ ei0,
                                                const int* __restrict__ ei1,
                                                float* __restrict__ he, int E){
  int t = threadIdx.x;
  int e = blockIdx.x*4 + (t >> 6);
  int d = t & 63;
  if(e >= E) return;
  float val = bf2f(buf[(size_t)e*64 + d]);
  int u = ei0[e], v = ei1[e];
  atomAddF(&he[(size_t)u*64 + d], val);
  atomAddF(&he[(size_t)v*64 + d], val);
}

// ---------------- gather + epilogue + graph pooling (in-place h' over xw) -------
template<bool WRITE_H>
__global__ __launch_bounds__(256) void kgather(u16* buf,            // read xw, write h'
                                               const float* __restrict__ he,
                                               const float* __restrict__ dinv,
                                               const int* __restrict__ ei0,
                                               const int* __restrict__ ei1,
                                               const float* __restrict__ imp,
                                               const float* __restrict__ bias,
                                               const int* __restrict__ batch,
                                               float* __restrict__ gh,
                                               int E, int layer){
  __shared__ float ghl[64*64];
  const int t = threadIdx.x;
  for(int i = t; i < 4096; i += 256) ghl[i] = 0.f;
  __syncthreads();

  const int d = t & 63, slot = t >> 6;
  const float bd = bias[d];

  for(int base = blockIdx.x*4; base < E; base += gridDim.x*4){
    int e = base + slot;
    if(e < E){
      int u = ei0[e], v = ei1[e];
      float iu = dinv[u], iv = dinv[v];
      float val = bf2f(buf[(size_t)e*64 + d]);
      val += he[(size_t)u*64 + d] * iu;
      val += he[(size_t)v*64 + d] * iv;
      // 1/c as float reciprocal (matches reference's 1/d-then-multiply)
      float rc = (iu > 0.f && iv > 0.f) ? (1.f/3.f) : ((iu > 0.f || iv > 0.f) ? 0.5f : 1.f);
      float o = fmaxf(val*rc + bd, 0.f) * imp[e];
      if(WRITE_H) buf[(size_t)e*64 + d] = f2bf(o);
      atomicAdd(&ghl[batch[u]*64 + d], o);
    }
  }
  __syncthreads();
  for(int i = t; i < 4096; i += 256){
    float v = ghl[i];
    if(v != 0.f) atomAddF(&gh[(i>>6)*192 + layer*64 + (i&63)], v);
  }
}

__global__ void kfinal(const float* __restrict__ gh, float* __restrict__ out, int n){
  int i = blockIdx.x*blockDim.x + threadIdx.x;
  if(i < n) out[i] = gh[i];   // output dtype = reference output dtype = float32
}

// ---------------- host ----------------
extern "C" void kernel_launch(void* const* d_in, const int* in_sizes, int n_in,
                              void* d_out, int out_size, void* d_ws, size_t ws_size,
                              hipStream_t stream) {
  const float* edge_attr = (const float*)d_in[1];
  const int*   ei        = (const int*)d_in[2];
  const int*   batch     = (const int*)d_in[3];
  const float* nimp      = (const float*)d_in[4];
  const float* Ws[3] = { (const float*)d_in[5], (const float*)d_in[7], (const float*)d_in[9] };
  const float* bs[3] = { (const float*)d_in[6], (const float*)d_in[8], (const float*)d_in[10] };

  const int E = in_sizes[1] / 32;   // edge_attr is (E, 32)
  const int N = in_sizes[4];        // node_imp is (N,)
  const int* ei0 = ei;
  const int* ei1 = ei + E;

  char* p = (char*)d_ws;
  auto carve = [&](size_t bytes)->char*{
    char* r = p; p += (bytes + 255) & ~(size_t)255; return r;
  };
  float* imp  = (float*)carve((size_t)E*4);
  int*   deg  = (int*)  carve((size_t)N*4);
  float* dinv = (float*)carve((size_t)N*4);
  float* he   = (float*)carve((size_t)N*64*4);
  u16*   buf  = (u16*)  carve((size_t)E*64*2);   // xw / h' in-place
  float* gh   = (float*)carve((size_t)64*192*4);

  kzero<<<(N+255)/256, 256, 0, stream>>>((float*)deg, N);
  kzero<<<(12288+255)/256, 256, 0, stream>>>(gh, 12288);
  kdeg<<<(E+255)/256, 256, 0, stream>>>(ei0, ei1, nimp, deg, imp, E);
  kdinv<<<(N+255)/256, 256, 0, stream>>>(deg, dinv, N);

  const int he4 = N*64/4;
  for(int l = 0; l < 3; l++){
    kzero4<<<(he4+255)/256, 256, 0, stream>>>((float4*)he, he4);
    if(l == 0) kgemm<32,true ><<<(E+31)/32, 256, 0, stream>>>(edge_attr, buf, Ws[0], imp, E);
    else       kgemm<64,false><<<(E+31)/32, 256, 0, stream>>>(nullptr,   buf, Ws[l], imp, E);
    kscatter<<<(E+3)/4, 256, 0, stream>>>(buf, ei0, ei1, he, E);
    if(l < 2) kgather<true ><<<2048, 256, 0, stream>>>(buf, he, dinv, ei0, ei1, imp, bs[l], batch, gh, E, l);
    else      kgather<false><<<2048, 256, 0, stream>>>(buf, he, dinv, ei0, ei1, imp, bs[l], batch, gh, E, l);
  }
  kfinal<<<(12288+255)/256, 256, 0, stream>>>(gh, (float*)d_out, 12288);
}

// Round 4
// 1435.434 us; speedup vs baseline: 1.8195x; 1.8195x over previous
//
#include <hip/hip_runtime.h>
#include <hip/hip_bf16.h>
#include <cstdint>
#include <cstddef>

typedef unsigned short u16;
typedef unsigned int   u32;
typedef short bf16x8 __attribute__((ext_vector_type(8)));   // 8 bf16 = 4 VGPRs
typedef float f32x4  __attribute__((ext_vector_type(4)));

__device__ __forceinline__ float bf2f(u16 v){ return __uint_as_float(((u32)v)<<16); }
__device__ __forceinline__ u16 f2bf(float f){
  u32 x = __float_as_uint(f);
  return (u16)((x + 0x7FFFu + ((x>>16)&1u)) >> 16);   // round-to-nearest-even
}
__device__ __forceinline__ void atomAddF(float* p, float v){ unsafeAtomicAdd(p, v); }

// ---------------- zero helpers ----------------
__global__ void kzero(float* p, int n){
  int i = blockIdx.x*blockDim.x + threadIdx.x;
  if(i < n) p[i] = 0.f;
}
__global__ void kzero4(float4* p, int n){
  int i = blockIdx.x*blockDim.x + threadIdx.x;
  if(i < n) p[i] = make_float4(0.f,0.f,0.f,0.f);
}

// ---------------- degrees + edge importance ----------------
__global__ void kdeg(const int* __restrict__ ei0, const int* __restrict__ ei1,
                     const float* __restrict__ nimp, int* __restrict__ deg,
                     float* __restrict__ imp, int E){
  int e = blockIdx.x*blockDim.x + threadIdx.x;
  if(e >= E) return;
  int u = ei0[e], v = ei1[e];
  atomicAdd(&deg[u], 1);
  atomicAdd(&deg[v], 1);
  imp[e] = fminf(nimp[u], nimp[v]);
}

__global__ void kdinv(const int* __restrict__ deg, float* __restrict__ dinv, int N){
  int i = blockIdx.x*blockDim.x + threadIdx.x;
  if(i >= N) return;
  int d = deg[i];
  dinv[i] = (d > 1) ? (1.f/(float)d) : 0.f;   // deg==1 hyperedges are dropped
}

// ---------------- W -> fragment-ready layout (bf16) ----------------
// slot s = tt*(NC*64) + c*64 + lane ; element j: wf[s*8+j] = W[c*32 + (lane>>4)*8 + j][tt*16 + (lane&15)]
template<int DIN>
__global__ void kprepw(const float* __restrict__ W, u16* __restrict__ wf){
  constexpr int NC = DIN/32;
  constexpr int SLOTS = 4*NC*64;
  int s = blockIdx.x*blockDim.x + threadIdx.x;
  if(s >= SLOTS) return;
  int lane = s & 63;
  int c    = (s >> 6) % NC;
  int tt   = s / (NC*64);
  int n  = tt*16 + (lane & 15);
  int k0 = c*32 + (lane >> 4)*8;
  #pragma unroll
  for(int j = 0; j < 8; j++)
    wf[(size_t)s*8 + j] = f2bf(W[(size_t)(k0 + j)*64 + n]);
}

// ---------------- MFMA GEMM + fused he-scatter ----------------
// buf[e][d] = sum_k h[e][k] * W[k][d]; then he[u]+= , he[v]+= (atomics).
// block = 256 thr = 4 waves; wave handles 16 edge-rows; full n=64 via 4 tiles.
// FIRST: h = edge_attr(fp32, DIN=32)*imp ; else h = buf rows (bf16, DIN=64), in-place.
template<int DIN, bool FIRST>
__global__ __launch_bounds__(256) void kgemm_mfma(const float* __restrict__ srcf,
                                                  u16* buf,          // read+write
                                                  const u16* __restrict__ wf,
                                                  const float* __restrict__ imp,
                                                  const int* __restrict__ ei0,
                                                  const int* __restrict__ ei1,
                                                  float* __restrict__ he,
                                                  int E){
  constexpr int NC = DIN/32;
  const int t    = threadIdx.x;
  const int wv   = t >> 6;
  const int lane = t & 63;
  const int quad = lane >> 4;
  const int l15  = lane & 15;
  const int row0 = blockIdx.x*64 + wv*16;
  if(row0 >= E) return;                      // E % 16 == 0: wave-granular tail

  // B fragments (4 n-tiles x NC k-chunks), L1-hot
  bf16x8 bfr[4*NC];
  #pragma unroll
  for(int i = 0; i < 4*NC; i++)
    bfr[i] = *(const bf16x8*)(wf + ((size_t)i*64 + lane)*8);

  // A fragments for this wave's 16 rows
  const int myrow = row0 + l15;
  bf16x8 afr[NC];
  if(FIRST){
    const float* s = srcf + (size_t)myrow*32 + quad*8;
    const float sc = imp[myrow];
    f32x4 v0 = *(const f32x4*)s;
    f32x4 v1 = *(const f32x4*)(s+4);
    bf16x8 a;
    a[0]=(short)f2bf(v0.x*sc); a[1]=(short)f2bf(v0.y*sc);
    a[2]=(short)f2bf(v0.z*sc); a[3]=(short)f2bf(v0.w*sc);
    a[4]=(short)f2bf(v1.x*sc); a[5]=(short)f2bf(v1.y*sc);
    a[6]=(short)f2bf(v1.z*sc); a[7]=(short)f2bf(v1.w*sc);
    afr[0] = a;
  } else {
    #pragma unroll
    for(int c = 0; c < NC; c++)
      afr[c] = *(const bf16x8*)(buf + (size_t)myrow*64 + c*32 + quad*8);
  }

  // accumulate: acc[tt] covers n = tt*16 .. +15
  f32x4 acc[4];
  #pragma unroll
  for(int tt = 0; tt < 4; tt++){
    f32x4 a = {0.f,0.f,0.f,0.f};
    #pragma unroll
    for(int c = 0; c < NC; c++)
      a = __builtin_amdgcn_mfma_f32_16x16x32_bf16(afr[c], bfr[tt*NC+c], a, 0, 0, 0);
    acc[tt] = a;
  }

  // epilogue: lane holds (row = row0 + quad*4 + r, col = tt*16 + l15)
  int us[4], vs[4];
  #pragma unroll
  for(int r = 0; r < 4; r++){
    int em = row0 + quad*4 + r;
    us[r] = ei0[em];
    vs[r] = ei1[em];
  }
  #pragma unroll
  for(int tt = 0; tt < 4; tt++){
    const int n = tt*16 + l15;
    #pragma unroll
    for(int r = 0; r < 4; r++){
      const int em = row0 + quad*4 + r;
      const float val = acc[tt][r];
      buf[(size_t)em*64 + n] = f2bf(val);
      atomAddF(&he[(size_t)us[r]*64 + n], val);
      atomAddF(&he[(size_t)vs[r]*64 + n], val);
    }
  }
}

// ---------------- gather + epilogue + graph pooling (in-place h' over xw) -------
template<bool WRITE_H>
__global__ __launch_bounds__(256) void kgather(u16* buf,            // read xw, write h'
                                               const float* __restrict__ he,
                                               const float* __restrict__ dinv,
                                               const int* __restrict__ ei0,
                                               const int* __restrict__ ei1,
                                               const float* __restrict__ imp,
                                               const float* __restrict__ bias,
                                               const int* __restrict__ batch,
                                               float* __restrict__ gh,
                                               int E, int layer){
  __shared__ float ghl[64*64];
  const int t = threadIdx.x;
  for(int i = t; i < 4096; i += 256) ghl[i] = 0.f;
  __syncthreads();

  const int d = t & 63, slot = t >> 6;
  const float bd = bias[d];

  for(int base = blockIdx.x*4; base < E; base += gridDim.x*4){
    int e = base + slot;
    if(e < E){
      int u = ei0[e], v = ei1[e];
      float iu = dinv[u], iv = dinv[v];
      float val = bf2f(buf[(size_t)e*64 + d]);
      val += he[(size_t)u*64 + d] * iu;
      val += he[(size_t)v*64 + d] * iv;
      float rc = (iu > 0.f && iv > 0.f) ? (1.f/3.f) : ((iu > 0.f || iv > 0.f) ? 0.5f : 1.f);
      float o = fmaxf(val*rc + bd, 0.f) * imp[e];
      if(WRITE_H) buf[(size_t)e*64 + d] = f2bf(o);
      atomicAdd(&ghl[batch[u]*64 + d], o);
    }
  }
  __syncthreads();
  for(int i = t; i < 4096; i += 256){
    float v = ghl[i];
    if(v != 0.f) atomAddF(&gh[(i>>6)*192 + layer*64 + (i&63)], v);
  }
}

__global__ void kfinal(const float* __restrict__ gh, float* __restrict__ out, int n){
  int i = blockIdx.x*blockDim.x + threadIdx.x;
  if(i < n) out[i] = gh[i];   // reference output dtype = float32
}

// ---------------- host ----------------
extern "C" void kernel_launch(void* const* d_in, const int* in_sizes, int n_in,
                              void* d_out, int out_size, void* d_ws, size_t ws_size,
                              hipStream_t stream) {
  const float* edge_attr = (const float*)d_in[1];
  const int*   ei        = (const int*)d_in[2];
  const int*   batch     = (const int*)d_in[3];
  const float* nimp      = (const float*)d_in[4];
  const float* Ws[3] = { (const float*)d_in[5], (const float*)d_in[7], (const float*)d_in[9] };
  const float* bs[3] = { (const float*)d_in[6], (const float*)d_in[8], (const float*)d_in[10] };

  const int E = in_sizes[1] / 32;   // edge_attr is (E, 32)
  const int N = in_sizes[4];        // node_imp is (N,)
  const int* ei0 = ei;
  const int* ei1 = ei + E;

  char* p = (char*)d_ws;
  auto carve = [&](size_t bytes)->char*{
    char* r = p; p += (bytes + 255) & ~(size_t)255; return r;
  };
  float* imp  = (float*)carve((size_t)E*4);
  int*   deg  = (int*)  carve((size_t)N*4);
  float* dinv = (float*)carve((size_t)N*4);
  float* he   = (float*)carve((size_t)N*64*4);
  u16*   buf  = (u16*)  carve((size_t)E*64*2);   // xw / h' in-place
  float* gh   = (float*)carve((size_t)64*192*4);
  u16*   wfs[3];
  for(int l = 0; l < 3; l++) wfs[l] = (u16*)carve((size_t)4096*2);

  kzero<<<(N+255)/256, 256, 0, stream>>>((float*)deg, N);
  kzero<<<(12288+255)/256, 256, 0, stream>>>(gh, 12288);
  kdeg<<<(E+255)/256, 256, 0, stream>>>(ei0, ei1, nimp, deg, imp, E);
  kdinv<<<(N+255)/256, 256, 0, stream>>>(deg, dinv, N);
  kprepw<32><<<1, 256, 0, stream>>>(Ws[0], wfs[0]);
  kprepw<64><<<2, 256, 0, stream>>>(Ws[1], wfs[1]);
  kprepw<64><<<2, 256, 0, stream>>>(Ws[2], wfs[2]);

  const int he4 = N*64/4;
  const int nb  = (E + 63)/64;
  for(int l = 0; l < 3; l++){
    kzero4<<<(he4+255)/256, 256, 0, stream>>>((float4*)he, he4);
    if(l == 0) kgemm_mfma<32,true ><<<nb, 256, 0, stream>>>(edge_attr, buf, wfs[0], imp, ei0, ei1, he, E);
    else       kgemm_mfma<64,false><<<nb, 256, 0, stream>>>(nullptr,   buf, wfs[l], imp, ei0, ei1, he, E);
    if(l < 2) kgather<true ><<<2048, 256, 0, stream>>>(buf, he, dinv, ei0, ei1, imp, bs[l], batch, gh, E, l);
    else      kgather<false><<<2048, 256, 0, stream>>>(buf, he, dinv, ei0, ei1, imp, bs[l], batch, gh, E, l);
  }
  kfinal<<<(12288+255)/256, 256, 0, stream>>>(gh, (float*)d_out, 12288);
}